// Round 9
// baseline (476.509 us; speedup 1.0000x reference)
//
#include <hip/hip_runtime.h>
#include <math.h>

namespace {
constexpr int H = 512, W = 512, NUM_ANCH = 6;
constexpr int N = H * W * NUM_ANCH;          // 1572864
constexpr int NG = N / 4;                    // 393216 groups of 4 anchors
constexpr int PREK = 4096;
constexpr int POSTK = 500;
constexpr float SCORE_THRESH = 0.1f;
constexpr float IOU_THRESH = 0.01f;
constexpr float DIR_OFFSET = 0.78539f;
constexpr float PERIOD = 3.14159265358979323846f; // f32(pi)
constexpr int LISTB_CAP = 8192;

// ---- workspace layout ----
// scores (N f32, 6.29 MB) is dead after k_compact; maskT+diag overlay it
// (written by k_maskgen, read by k_tail — strictly later in the stream).
constexpr size_t oScores = 0;                                  // N f32
constexpr size_t oMaskT  = 0;                                  // 64*4096 u64 (2 MB) overlay
constexpr size_t oDiag   = (size_t)PREK * 64 * 8;              // PREK u64 (32 KB) overlay
constexpr size_t oHist12 = (size_t)N * 4;                      // 4096 u32
constexpr size_t oHistA  = oHist12 + 4096 * 4;                 // 1024 u32
constexpr size_t oHistB  = oHistA + 1024 * 4;                  // 1024 u32
constexpr size_t oMeta   = oHistB + 1024 * 4;                  // 64 u32
constexpr size_t oListAS = oMeta + 64 * 4;                     // PREK f32
constexpr size_t oListAI = oListAS + PREK * 4;                 // PREK u32
constexpr size_t oListB  = oListAI + PREK * 4;                 // LISTB_CAP u32
constexpr size_t oTopS   = oListB + (size_t)LISTB_CAP * 4;     // PREK f32
constexpr size_t oTopI   = oTopS + PREK * 4;                   // PREK u32
constexpr size_t oTB     = oTopI + PREK * 4;                   // PREK*7 f32
constexpr size_t oB4     = oTB + (size_t)PREK * 7 * 4;         // PREK float4
constexpr size_t oLabel  = oB4 + (size_t)PREK * 16;            // PREK u32
constexpr size_t oValidW = oLabel + PREK * 4;                  // 64 u64
constexpr size_t WS_NEED = oValidW + 64 * 8;
// meta slots: 0:T1 1:G1 2:T2 3:G2 12:T3 5:G 6:E 7:cntA 8:cntB 10,11:scratch
}

__device__ __forceinline__ float sigmoid_rn(float x) {
  // correctly-rounded-to-f32 sigmoid via double (matches np f64 reference)
  return (float)(1.0 / (1.0 + exp(-(double)x)));
}

__device__ __forceinline__ unsigned long long rdl64(unsigned long long v, int src) {
  unsigned lo = (unsigned)__builtin_amdgcn_readlane((int)(unsigned)v, src);
  unsigned hi = (unsigned)__builtin_amdgcn_readlane((int)(unsigned)(v >> 32), src);
  return ((unsigned long long)hi << 32) | lo;
}

// ---- 1: per-anchor score + 12-bit histogram (grid-stride, 256 blocks) ----
__global__ __launch_bounds__(256) void k_scores(const float4* __restrict__ cls4,
                                                float4* __restrict__ scores4,
                                                unsigned* __restrict__ hist12) {
  __shared__ unsigned h[4096];
  for (int t = threadIdx.x; t < 4096; t += 256) h[t] = 0;
  __syncthreads();
  int stride = gridDim.x * 256;
  for (int g = blockIdx.x * 256 + threadIdx.x; g < NG; g += stride) {
    float4 a = cls4[(size_t)g * 3 + 0];
    float4 b = cls4[(size_t)g * 3 + 1];
    float4 c = cls4[(size_t)g * 3 + 2];
    float m0 = fmaxf(a.x, fmaxf(a.y, a.z));
    float m1 = fmaxf(a.w, fmaxf(b.x, b.y));
    float m2 = fmaxf(b.z, fmaxf(b.w, c.x));
    float m3 = fmaxf(c.y, fmaxf(c.z, c.w));
    float s0 = sigmoid_rn(m0); s0 = (s0 >= SCORE_THRESH) ? s0 : 0.0f;
    float s1 = sigmoid_rn(m1); s1 = (s1 >= SCORE_THRESH) ? s1 : 0.0f;
    float s2 = sigmoid_rn(m2); s2 = (s2 >= SCORE_THRESH) ? s2 : 0.0f;
    float s3 = sigmoid_rn(m3); s3 = (s3 >= SCORE_THRESH) ? s3 : 0.0f;
    scores4[g] = make_float4(s0, s1, s2, s3);
    atomicAdd(&h[__float_as_uint(s0) >> 20], 1u);
    atomicAdd(&h[__float_as_uint(s1) >> 20], 1u);
    atomicAdd(&h[__float_as_uint(s2) >> 20], 1u);
    atomicAdd(&h[__float_as_uint(s3) >> 20], 1u);
  }
  __syncthreads();
  for (int t = threadIdx.x; t < 4096; t += 256) {
    unsigned v = h[t];
    if (v) atomicAdd(&hist12[t], v);
  }
}

// ---- generic scan: find bin where cumulative-from-top crosses R ----
__global__ void k_scan(const unsigned* __restrict__ hist, unsigned* __restrict__ meta,
                       int nbins, int prevGslot, int outBin, int outG, int outE) {
  __shared__ unsigned part[256];
  int t = threadIdx.x;
  int chunk = nbins >> 8;
  unsigned prevG = (prevGslot >= 0) ? meta[prevGslot] : 0u;
  unsigned R = (unsigned)PREK - prevG;
  unsigned s = 0;
  for (int c = 0; c < chunk; ++c) s += hist[t * chunk + c];
  part[t] = s;
  __syncthreads();
  for (int off = 1; off < 256; off <<= 1) {
    unsigned v = part[t];
    unsigned add = (t + off < 256) ? part[t + off] : 0u;
    __syncthreads();
    part[t] = v + add;
    __syncthreads();
  }
  unsigned cum = (t == 255) ? 0u : part[t + 1];
  for (int c = chunk - 1; c >= 0; --c) {
    unsigned hv = hist[t * chunk + c];
    unsigned above = cum;
    cum += hv;
    if (cum >= R && above < R) {
      meta[outBin] = (unsigned)(t * chunk + c);
      meta[outG] = prevG + above;
      meta[outE] = R - above;
    }
  }
}

// ---- refine histograms, 4-wide, grid-stride ----
__global__ __launch_bounds__(256) void k_refine(const float4* __restrict__ scores4,
                                                unsigned* __restrict__ hist,
                                                const unsigned* __restrict__ meta, int mode) {
  __shared__ unsigned h[1024];
  for (int t = threadIdx.x; t < 1024; t += 256) h[t] = 0;
  __syncthreads();
  unsigned m0 = meta[0];
  unsigned pref22 = (m0 << 10) | meta[2];
  int stride = gridDim.x * 256;
  for (int g = blockIdx.x * 256 + threadIdx.x; g < NG; g += stride) {
    float4 s = scores4[g];
    unsigned bb[4] = {__float_as_uint(s.x), __float_as_uint(s.y),
                      __float_as_uint(s.z), __float_as_uint(s.w)};
#pragma unroll
    for (int k = 0; k < 4; ++k) {
      unsigned bits = bb[k];
      if (mode == 0) {
        if ((bits >> 20) == m0) atomicAdd(&h[(bits >> 10) & 1023u], 1u);
      } else {
        if ((bits >> 10) == pref22) atomicAdd(&h[bits & 1023u], 1u);
      }
    }
  }
  __syncthreads();
  for (int t = threadIdx.x; t < 1024; t += 256) {
    unsigned v = h[t];
    if (v) atomicAdd(&hist[t], v);
  }
}

// ---- compact > thr and == thr, 4-wide, grid-stride ----
__global__ __launch_bounds__(256) void k_compact(const float4* __restrict__ scores4,
                                                 unsigned* __restrict__ meta,
                                                 float* __restrict__ laS, unsigned* __restrict__ laI,
                                                 unsigned* __restrict__ lb) {
  unsigned thr = (meta[0] << 20) | (meta[2] << 10) | meta[12];
  int stride = gridDim.x * 256;
  for (int g = blockIdx.x * 256 + threadIdx.x; g < NG; g += stride) {
    float4 s = scores4[g];
    float sv[4] = {s.x, s.y, s.z, s.w};
#pragma unroll
    for (int k = 0; k < 4; ++k) {
      unsigned bits = __float_as_uint(sv[k]);
      int n = g * 4 + k;
      if (bits > thr) {
        unsigned pos = atomicAdd(&meta[7], 1u);
        if (pos < (unsigned)PREK) { laS[pos] = sv[k]; laI[pos] = (unsigned)n; }
      } else if (bits == thr) {
        unsigned pos = atomicAdd(&meta[8], 1u);
        if (pos < (unsigned)LISTB_CAP) lb[pos] = (unsigned)n;
      }
    }
  }
}

// ---- fused: tie-resolution + bitonic sort + validW emission ----
__global__ __launch_bounds__(1024) void k_select(const unsigned* __restrict__ meta,
                                                 const float* __restrict__ laS,
                                                 const unsigned* __restrict__ laI,
                                                 const unsigned* __restrict__ lb,
                                                 float* __restrict__ topS,
                                                 unsigned* __restrict__ topI,
                                                 unsigned long long* __restrict__ validW) {
  __shared__ unsigned arrB[LISTB_CAP];            // 32 KB
  __shared__ unsigned long long arr[PREK];        // 32 KB
  int t = threadIdx.x;
  unsigned E = meta[6];
  unsigned G = meta[7];
  unsigned cntB = meta[8];
  if (cntB > (unsigned)LISTB_CAP) cntB = LISTB_CAP;
  unsigned thr = (meta[0] << 20) | (meta[2] << 10) | meta[12];

  if (E != 0) {                                   // uniform branch
    int n2 = 2;
    while ((unsigned)n2 < cntB) n2 <<= 1;
    for (int i = t; i < n2; i += 1024) arrB[i] = (i < (int)cntB) ? lb[i] : 0xFFFFFFFFu;
    __syncthreads();
    if (cntB != E) {
      for (int k = 2; k <= n2; k <<= 1) {
        for (int j = k >> 1; j > 0; j >>= 1) {
          for (int p = t; p < n2 / 2; p += 1024) {
            int i = ((p / j) * (2 * j)) + (p % j);
            int l = i + j;
            bool up = ((i & k) == 0);
            unsigned a = arrB[i], b = arrB[l];
            if ((a > b) == up) { arrB[i] = b; arrB[l] = a; }
          }
          __syncthreads();
        }
      }
    }
    for (int i = t; i < (int)E; i += 1024)
      arr[G + i] = ((unsigned long long)thr << 32) | (unsigned long long)(~arrB[i]);
  }
  __syncthreads();
  for (int i = t; i < PREK; i += 1024)
    if (i < (int)G)
      arr[i] = ((unsigned long long)__float_as_uint(laS[i]) << 32) |
               (unsigned long long)(~laI[i]);
  __syncthreads();
  for (int k = 2; k <= PREK; k <<= 1) {
    for (int j = k >> 1; j > 0; j >>= 1) {
      for (int p = t; p < PREK / 2; p += 1024) {
        int i = ((p / j) * (2 * j)) + (p % j);
        int l = i + j;
        bool up = ((i & k) == 0); // descending
        unsigned long long a = arr[i], b = arr[l];
        if ((a < b) == up) { arr[i] = b; arr[l] = a; }
      }
      __syncthreads();
    }
  }
  for (int i = t; i < PREK; i += 1024) {
    unsigned long long key = arr[i];
    unsigned sb = (unsigned)(key >> 32);
    topS[i] = __uint_as_float(sb);
    topI[i] = ~((unsigned)key);
    unsigned long long bal = __ballot(sb != 0);
    if ((t & 63) == 0) validW[i >> 6] = bal;
  }
}

// ---- decode selected boxes ----
__global__ void k_decode(const float* __restrict__ cls, const float* __restrict__ box,
                         const float* __restrict__ dir, const float* __restrict__ anc,
                         const unsigned* __restrict__ topI,
                         float* __restrict__ tb, float4* __restrict__ b4,
                         unsigned* __restrict__ label) {
  int i = blockIdx.x * blockDim.x + threadIdx.x;
  if (i >= PREK) return;
  size_t idx = (size_t)topI[i];
  const float* a = anc + idx * 7;
  const float* b = box + idx * 7;
  float xa = a[0], ya = a[1], za = a[2], dxa = a[3], dya = a[4], dza = a[5], ra = a[6];
  float xt = b[0], yt = b[1], zt = b[2], dxt = b[3], dyt = b[4], dzt = b[5], rt = b[6];
  za = za + dza * 0.5f;
  float diagl = sqrtf(dxa * dxa + dya * dya);
  float xg = xt * diagl + xa;
  float yg = yt * diagl + ya;
  float zg = zt * dza + za;
  float dxg = (float)exp((double)dxt) * dxa;
  float dyg = (float)exp((double)dyt) * dya;
  float dzg = (float)exp((double)dzt) * dza;
  float rg = rt + ra;
  zg = zg - dzg * 0.5f;
  float d0 = dir[idx * 2], d1 = dir[idx * 2 + 1];
  float dl = (d1 > d0) ? 1.0f : 0.0f;
  float val = rg - DIR_OFFSET;
  val = val - floorf(val / PERIOD) * PERIOD;
  float rot = val + DIR_OFFSET + PERIOD * dl;
  float l0 = cls[idx * 3 + 0];
  float l1 = cls[idx * 3 + 1];
  float l2 = cls[idx * 3 + 2];
  unsigned lab = 1;
  float bestl = l0;
  if (l1 > bestl) { bestl = l1; lab = 2; }
  if (l2 > bestl) { bestl = l2; lab = 3; }
  tb[i * 7 + 0] = xg; tb[i * 7 + 1] = yg; tb[i * 7 + 2] = zg;
  tb[i * 7 + 3] = dxg; tb[i * 7 + 4] = dyg; tb[i * 7 + 5] = dzg;
  tb[i * 7 + 6] = rot;
  float X1 = xg - dxg * 0.5f, X2 = xg + dxg * 0.5f;
  float Y1 = yg - dyg * 0.5f, Y2 = yg + dyg * 0.5f;
  b4[i] = make_float4(X1, Y1, X2, Y2);
  label[i] = lab;
}

// ---- pairwise IoU bitmask, TRANSPOSED (column-chunk-major) + diag ----
// maskT[w][i] (w=0..63, i=0..4095): bit j = box i suppresses box w*64+j.
// Only row-blocks rb < w are written (rb==w goes to diag; rb>w is all-zero and
// never read). Work unit = (w, rb) pair; 2080 pairs over 1024 waves.
__global__ __launch_bounds__(256) void k_maskgen(const float4* __restrict__ b4,
                                                 unsigned long long* __restrict__ maskT,
                                                 unsigned long long* __restrict__ diag) {
  __shared__ float4 sb[PREK];   // 64 KB
  int t = threadIdx.x;
  for (int i = t; i < PREK; i += 256) sb[i] = b4[i];
  __syncthreads();
  int lane = t & 63, wv = t >> 6;
  int gw = blockIdx.x * 4 + wv;           // 0..1023
  for (int p = gw; p < 2080; p += 1024) {
    int w = 0;                             // decode p -> (w, rb), rb <= w
    while (((w + 1) * (w + 2)) / 2 <= p) ++w;
    int rb = p - (w * (w + 1)) / 2;
    bool isdiag = (rb == w);
    float4 bj = sb[(w << 6) + lane];
    float Aj = (bj.z - bj.x) * (bj.w - bj.y);
    unsigned long long myword = 0;
    for (int rr = 0; rr < 64; ++rr) {
      float4 bi = sb[(rb << 6) + rr];      // uniform -> LDS broadcast
      float Ai = (bi.z - bi.x) * (bi.w - bi.y);
      float ix = fminf(bi.z, bj.z) - fmaxf(bi.x, bj.x); ix = fmaxf(ix, 0.0f);
      float iy = fminf(bi.w, bj.w) - fmaxf(bi.y, bj.y); iy = fmaxf(iy, 0.0f);
      float inter = ix * iy;
      float iou = inter / (Ai + Aj - inter + 1e-6f);
      bool cond = (iou > IOU_THRESH) && (!isdiag || lane > rr);
      unsigned long long word = __ballot(cond);
      if (lane == rr) myword = word;
    }
    if (isdiag) diag[(w << 6) + lane] = myword;
    else maskT[((size_t)w << 12) + (rb << 6) + lane] = myword;
  }
}

// ---- fused greedy NMS: wave 0 = serial chain (LDS-only), waves 1-7 = stage ----
__global__ __launch_bounds__(512) void k_tail(const float* __restrict__ topS,
                                              const float* __restrict__ tb,
                                              const unsigned* __restrict__ label,
                                              const unsigned long long* __restrict__ validW,
                                              const unsigned long long* __restrict__ maskT,
                                              const unsigned long long* __restrict__ diag,
                                              float* __restrict__ out) {
  __shared__ unsigned long long bufU64[8192];   // 64 KB: 2 x 4096 double buffer
  uint4* bufV = (uint4*)bufU64;
  const uint4* mT4 = (const uint4*)maskT;       // 2048 uint4 per column block
  int t = threadIdx.x;
  int tt = t - 64;                              // helper index 0..447
  uint4 pf0, pf1, pf2, pf3, pf4;
  int i0 = tt, i1 = tt + 448, i2 = tt + 896, i3 = tt + 1344, i4 = tt + 1792;
  // wave-0 per-lane state
  unsigned long long valid_l = 0, keep_l = 0, m_cur = 0, m_n1 = 0;
  if (t < 64) {
    valid_l = validW[t];
    m_cur = diag[t];            // diag word of row t (chunk 0)
    m_n1  = diag[64 + t];       // chunk 1
  } else {
    // prologue: stage block 0, then issue loads for block 1
    pf0 = mT4[i0]; pf1 = mT4[i1]; pf2 = mT4[i2]; pf3 = mT4[i3];
    if (i4 < 2048) pf4 = mT4[i4];
    bufV[i0] = pf0; bufV[i1] = pf1; bufV[i2] = pf2; bufV[i3] = pf3;
    if (i4 < 2048) bufV[i4] = pf4;
    pf0 = mT4[2048 + i0]; pf1 = mT4[2048 + i1]; pf2 = mT4[2048 + i2]; pf3 = mT4[2048 + i3];
    if (i4 < 2048) pf4 = mT4[2048 + i4];
  }
  __syncthreads();
  for (int c = 0; c < 64; ++c) {
    if (t < 64) {
      int lane = t;
      unsigned long long m_n2 = 0;
      if (c + 2 < 64) m_n2 = diag[((c + 2) << 6) + lane];
      // lazy removed word for chunk c: each lane ORs maskT[c][rows it kept]
      unsigned long long acc = 0;
      unsigned long long kl = keep_l;            // nonzero only for lanes < c
      int lbase = ((c & 1) << 12) + (lane << 6);
      while (kl) {
        int b = __ffsll((long long)kl) - 1;
        kl &= kl - 1;
        acc |= bufU64[lbase + b];
      }
      unsigned aLo = (unsigned)acc, aHi = (unsigned)(acc >> 32);
#pragma unroll
      for (int off = 1; off < 64; off <<= 1) {
        aLo |= (unsigned)__shfl_xor((int)aLo, off, 64);
        aHi |= (unsigned)__shfl_xor((int)aHi, off, 64);
      }
      unsigned long long removedW = ((unsigned long long)aHi << 32) | aLo;
      unsigned long long valC = rdl64(valid_l, c);
      unsigned long long pending = valC & ~removedW;
      unsigned long long kept = 0;
      unsigned mlo = (unsigned)m_cur, mhi = (unsigned)(m_cur >> 32);
      while (pending) {
        int b = __ffsll((long long)pending) - 1;
        b = __builtin_amdgcn_readfirstlane(b);
        kept |= (1ull << b);
        unsigned long long mb =
            ((unsigned long long)(unsigned)__builtin_amdgcn_readlane((int)mhi, b) << 32) |
            (unsigned long long)(unsigned)__builtin_amdgcn_readlane((int)mlo, b);
        pending &= (pending - 1);
        pending &= ~mb;
      }
      if (lane == c) keep_l = kept;
      m_cur = m_n1;
      m_n1 = m_n2;
    } else {
      if (c + 1 < 64) {
        // write block c+1 (loads issued last iteration), issue block c+2
        int half = ((c + 1) & 1) << 11;          // uint4 offset
        bufV[half + i0] = pf0; bufV[half + i1] = pf1;
        bufV[half + i2] = pf2; bufV[half + i3] = pf3;
        if (i4 < 2048) bufV[half + i4] = pf4;
        if (c + 2 < 64) {
          size_t src = (size_t)(c + 2) << 11;
          pf0 = mT4[src + i0]; pf1 = mT4[src + i1];
          pf2 = mT4[src + i2]; pf3 = mT4[src + i3];
          if (i4 < 2048) pf4 = mT4[src + i4];
        }
      }
    }
    __syncthreads();
  }
  // ---- output phase (overlay onto buf; greedy is done) ----
  unsigned long long* kwS = bufU64;              // 64 u64
  int* part = (int*)(bufU64 + 64);               // 512 int (2 KB)
  short* keptList = (short*)(bufU64 + 320);      // 4096 short (8 KB)
  short* nonKept  = (short*)(bufU64 + 1344);     // 4096 short (8 KB)
  if (t < 64) kwS[t] = keep_l;
  __syncthreads();
  int base = t * 8;
  int cnt = 0;
  for (int e = 0; e < 8; ++e) {
    int i = base + e;
    cnt += (int)((kwS[i >> 6] >> (i & 63)) & 1ull);
  }
  part[t] = cnt;
  __syncthreads();
  for (int off = 1; off < 512; off <<= 1) {
    int v = part[t];
    int add = (t >= off) ? part[t - off] : 0;
    __syncthreads();
    part[t] = v + add;
    __syncthreads();
  }
  int kbase = part[t] - cnt;
  int nbase = base - kbase;
  for (int e = 0; e < 8; ++e) {
    int i = base + e;
    bool kp = ((kwS[i >> 6] >> (i & 63)) & 1ull) != 0;
    if (kp) keptList[kbase++] = (short)i;
    else nonKept[nbase++] = (short)i;
  }
  __syncthreads();
  int keptCount = part[511];
  for (int k = t; k < POSTK; k += 512) {
    int i;
    float s;
    if (k < keptCount) { i = keptList[k]; s = topS[i]; }
    else { i = nonKept[k - keptCount]; s = 0.0f; }
    for (int c = 0; c < 7; ++c) out[k * 8 + c] = tb[i * 7 + c];
    out[k * 8 + 7] = s;
    out[POSTK * 8 + k] = (float)label[i];
  }
}

extern "C" void kernel_launch(void* const* d_in, const int* in_sizes, int n_in,
                              void* d_out, int out_size, void* d_ws, size_t ws_size,
                              hipStream_t stream) {
  const float* cls = (const float*)d_in[0];
  const float* box = (const float*)d_in[1];
  const float* dir = (const float*)d_in[2];
  const float* anc = (const float*)d_in[3];
  float* out = (float*)d_out;
  char* ws = (char*)d_ws;
  if (ws_size < WS_NEED) return;

  float* scores = (float*)(ws + oScores);
  unsigned* hist12 = (unsigned*)(ws + oHist12);
  unsigned* histA = (unsigned*)(ws + oHistA);
  unsigned* histB = (unsigned*)(ws + oHistB);
  unsigned* meta = (unsigned*)(ws + oMeta);
  float* laS = (float*)(ws + oListAS);
  unsigned* laI = (unsigned*)(ws + oListAI);
  unsigned* lb = (unsigned*)(ws + oListB);
  float* topS = (float*)(ws + oTopS);
  unsigned* topI = (unsigned*)(ws + oTopI);
  float* tb = (float*)(ws + oTB);
  float4* b4 = (float4*)(ws + oB4);
  unsigned* label = (unsigned*)(ws + oLabel);
  unsigned long long* validW = (unsigned long long*)(ws + oValidW);
  unsigned long long* maskT = (unsigned long long*)(ws + oMaskT);
  unsigned long long* diag = (unsigned long long*)(ws + oDiag);

  hipMemsetAsync(ws + oHist12, 0, (oListAS - oHist12), stream);

  k_scores<<<256, 256, 0, stream>>>((const float4*)cls, (float4*)scores, hist12);
  k_scan<<<1, 256, 0, stream>>>(hist12, meta, 4096, -1, 0, 1, 10);
  k_refine<<<256, 256, 0, stream>>>((const float4*)scores, histA, meta, 0);
  k_scan<<<1, 256, 0, stream>>>(histA, meta, 1024, 1, 2, 3, 11);
  k_refine<<<256, 256, 0, stream>>>((const float4*)scores, histB, meta, 1);
  k_scan<<<1, 256, 0, stream>>>(histB, meta, 1024, 3, 12, 5, 6);
  k_compact<<<256, 256, 0, stream>>>((const float4*)scores, meta, laS, laI, lb);
  k_select<<<1, 1024, 0, stream>>>(meta, laS, laI, lb, topS, topI, validW);
  k_decode<<<PREK / 256, 256, 0, stream>>>(cls, box, dir, anc, topI, tb, b4, label);
  k_maskgen<<<256, 256, 0, stream>>>(b4, maskT, diag);
  k_tail<<<1, 512, 0, stream>>>(topS, tb, label, validW, maskT, diag, out);
}

// Round 10
// 220.251 us; speedup vs baseline: 2.1635x; 2.1635x over previous
//
#include <hip/hip_runtime.h>
#include <math.h>

namespace {
constexpr int H = 512, W = 512, NUM_ANCH = 6;
constexpr int N = H * W * NUM_ANCH;          // 1572864
constexpr int NG = N / 4;                    // 393216 groups of 4 anchors
constexpr int PREK = 4096;
constexpr int POSTK = 500;
constexpr float SCORE_THRESH = 0.1f;
constexpr float IOU_THRESH = 0.01f;
constexpr float DIR_OFFSET = 0.78539f;
constexpr float PERIOD = 3.14159265358979323846f; // f32(pi)
constexpr int LISTB_CAP = 8192;

// ---- workspace layout ----
// scores (N f32, 6.29 MB) is dead after k_compactS; mask+diag2 overlay it
// (written by k_maskgen, read by k_tail — strictly later in the stream).
constexpr size_t oScores = 0;                                  // N f32
constexpr size_t oMask   = 0;                                  // PREK*64 u64 (2 MB) overlay
constexpr size_t oDiag2  = (size_t)PREK * 64 * 8;              // 32*2*64*2 u64 (64 KB) overlay
constexpr size_t oHist12 = (size_t)N * 4;                      // 4096 u32
constexpr size_t oHistA  = oHist12 + 4096 * 4;                 // 1024 u32
constexpr size_t oHistB  = oHistA + 1024 * 4;                  // 1024 u32
constexpr size_t oMeta   = oHistB + 1024 * 4;                  // 64 u32
constexpr size_t oListAS = oMeta + 64 * 4;                     // PREK f32
constexpr size_t oListAI = oListAS + PREK * 4;                 // PREK u32
constexpr size_t oListB  = oListAI + PREK * 4;                 // LISTB_CAP u32
constexpr size_t oTopS   = oListB + (size_t)LISTB_CAP * 4;     // PREK f32
constexpr size_t oTopI   = oTopS + PREK * 4;                   // PREK u32
constexpr size_t oTB     = oTopI + PREK * 4;                   // PREK*7 f32
constexpr size_t oB4     = oTB + (size_t)PREK * 7 * 4;         // PREK float4
constexpr size_t oLabel  = oB4 + (size_t)PREK * 16;            // PREK u32
constexpr size_t oValidW = oLabel + PREK * 4;                  // 64 u64
constexpr size_t WS_NEED = oValidW + 64 * 8;
// meta slots: 0:T1 1:ab1 2:T2 3:ab1+ab2 12:T3 6:E 7:cntA(G) 8:cntB
}

__device__ __forceinline__ float sigmoid_rn(float x) {
  // correctly-rounded-to-f32 sigmoid via double (matches np f64 reference)
  return (float)(1.0 / (1.0 + exp(-(double)x)));
}

__device__ __forceinline__ unsigned long long rdl64(unsigned long long v, int src) {
  unsigned lo = (unsigned)__builtin_amdgcn_readlane((int)(unsigned)v, src);
  unsigned hi = (unsigned)__builtin_amdgcn_readlane((int)(unsigned)(v >> 32), src);
  return ((unsigned long long)hi << 32) | lo;
}

__device__ __forceinline__ unsigned long long rl2(unsigned lo, unsigned hi, int ln) {
  unsigned a = (unsigned)__builtin_amdgcn_readlane((int)lo, ln);
  unsigned b = (unsigned)__builtin_amdgcn_readlane((int)hi, ln);
  return ((unsigned long long)b << 32) | a;
}

// block-wide (256 thr) scan over hist: find bin where cumulative-from-top
// crosses R. part = LDS[258]. Returns (bin, above) to all threads.
__device__ __forceinline__ void scan_find(const unsigned* __restrict__ hist, int nbins,
                                          unsigned R, unsigned& bin, unsigned& above,
                                          unsigned* part) {
  int t = threadIdx.x;
  int chunk = nbins >> 8;
  unsigned s = 0;
  for (int c = 0; c < chunk; ++c) s += hist[t * chunk + c];
  part[t] = s;
  __syncthreads();
  for (int off = 1; off < 256; off <<= 1) {
    unsigned v = part[t];
    unsigned add = (t + off < 256) ? part[t + off] : 0u;
    __syncthreads();
    part[t] = v + add;
    __syncthreads();
  }
  unsigned cum = (t == 255) ? 0u : part[t + 1];
  for (int c = chunk - 1; c >= 0; --c) {
    unsigned hv = hist[t * chunk + c];
    unsigned ab = cum;
    cum += hv;
    if (cum >= R && ab < R) { part[256] = (unsigned)(t * chunk + c); part[257] = ab; }
  }
  __syncthreads();
  bin = part[256];
  above = part[257];
  __syncthreads();
}

// ---- 1: per-anchor score + 12-bit histogram (grid-stride, 256 blocks) ----
__global__ __launch_bounds__(256) void k_scores(const float4* __restrict__ cls4,
                                                float4* __restrict__ scores4,
                                                unsigned* __restrict__ hist12) {
  __shared__ unsigned h[4096];
  for (int t = threadIdx.x; t < 4096; t += 256) h[t] = 0;
  __syncthreads();
  int stride = gridDim.x * 256;
  for (int g = blockIdx.x * 256 + threadIdx.x; g < NG; g += stride) {
    float4 a = cls4[(size_t)g * 3 + 0];
    float4 b = cls4[(size_t)g * 3 + 1];
    float4 c = cls4[(size_t)g * 3 + 2];
    float m0 = fmaxf(a.x, fmaxf(a.y, a.z));
    float m1 = fmaxf(a.w, fmaxf(b.x, b.y));
    float m2 = fmaxf(b.z, fmaxf(b.w, c.x));
    float m3 = fmaxf(c.y, fmaxf(c.z, c.w));
    float s0 = sigmoid_rn(m0); s0 = (s0 >= SCORE_THRESH) ? s0 : 0.0f;
    float s1 = sigmoid_rn(m1); s1 = (s1 >= SCORE_THRESH) ? s1 : 0.0f;
    float s2 = sigmoid_rn(m2); s2 = (s2 >= SCORE_THRESH) ? s2 : 0.0f;
    float s3 = sigmoid_rn(m3); s3 = (s3 >= SCORE_THRESH) ? s3 : 0.0f;
    scores4[g] = make_float4(s0, s1, s2, s3);
    atomicAdd(&h[__float_as_uint(s0) >> 20], 1u);
    atomicAdd(&h[__float_as_uint(s1) >> 20], 1u);
    atomicAdd(&h[__float_as_uint(s2) >> 20], 1u);
    atomicAdd(&h[__float_as_uint(s3) >> 20], 1u);
  }
  __syncthreads();
  for (int t = threadIdx.x; t < 4096; t += 256) {
    unsigned v = h[t];
    if (v) atomicAdd(&hist12[t], v);
  }
}

// ---- refine A: scan hist12 -> T1; histogram bits[19:10] within bin T1 ----
__global__ __launch_bounds__(256) void k_refineA(const float4* __restrict__ scores4,
                                                 const unsigned* __restrict__ hist12,
                                                 unsigned* __restrict__ histA,
                                                 unsigned* __restrict__ meta) {
  __shared__ unsigned h[1024];
  __shared__ unsigned part[258];
  for (int t = threadIdx.x; t < 1024; t += 256) h[t] = 0;
  unsigned T1, ab1;
  scan_find(hist12, 4096, PREK, T1, ab1, part);
  if (threadIdx.x == 0) { meta[0] = T1; meta[1] = ab1; }   // identical across blocks
  int stride = gridDim.x * 256;
  for (int g = blockIdx.x * 256 + threadIdx.x; g < NG; g += stride) {
    float4 s = scores4[g];
    unsigned bb[4] = {__float_as_uint(s.x), __float_as_uint(s.y),
                      __float_as_uint(s.z), __float_as_uint(s.w)};
#pragma unroll
    for (int k = 0; k < 4; ++k)
      if ((bb[k] >> 20) == T1) atomicAdd(&h[(bb[k] >> 10) & 1023u], 1u);
  }
  __syncthreads();
  for (int t = threadIdx.x; t < 1024; t += 256) {
    unsigned v = h[t];
    if (v) atomicAdd(&histA[t], v);
  }
}

// ---- refine B: scan histA -> T2; histogram bits[9:0] within prefix ----
__global__ __launch_bounds__(256) void k_refineB(const float4* __restrict__ scores4,
                                                 const unsigned* __restrict__ histA,
                                                 unsigned* __restrict__ histB,
                                                 unsigned* __restrict__ meta) {
  __shared__ unsigned h[1024];
  __shared__ unsigned part[258];
  for (int t = threadIdx.x; t < 1024; t += 256) h[t] = 0;
  unsigned m0 = meta[0], prev = meta[1];
  unsigned T2, ab2;
  scan_find(histA, 1024, PREK - prev, T2, ab2, part);
  if (threadIdx.x == 0) { meta[2] = T2; meta[3] = prev + ab2; }
  unsigned pref22 = (m0 << 10) | T2;
  int stride = gridDim.x * 256;
  for (int g = blockIdx.x * 256 + threadIdx.x; g < NG; g += stride) {
    float4 s = scores4[g];
    unsigned bb[4] = {__float_as_uint(s.x), __float_as_uint(s.y),
                      __float_as_uint(s.z), __float_as_uint(s.w)};
#pragma unroll
    for (int k = 0; k < 4; ++k)
      if ((bb[k] >> 10) == pref22) atomicAdd(&h[bb[k] & 1023u], 1u);
  }
  __syncthreads();
  for (int t = threadIdx.x; t < 1024; t += 256) {
    unsigned v = h[t];
    if (v) atomicAdd(&histB[t], v);
  }
}

// ---- compact: scan histB -> T3/E; compact >thr and ==thr ----
__global__ __launch_bounds__(256) void k_compactS(const float4* __restrict__ scores4,
                                                  const unsigned* __restrict__ histB,
                                                  unsigned* __restrict__ meta,
                                                  float* __restrict__ laS,
                                                  unsigned* __restrict__ laI,
                                                  unsigned* __restrict__ lb) {
  __shared__ unsigned part[258];
  unsigned m0 = meta[0], m2 = meta[2], prev = meta[3];
  unsigned R3 = PREK - prev;
  unsigned T3, ab3;
  scan_find(histB, 1024, R3, T3, ab3, part);
  if (threadIdx.x == 0) { meta[12] = T3; meta[6] = R3 - ab3; }
  unsigned thr = (m0 << 20) | (m2 << 10) | T3;
  int stride = gridDim.x * 256;
  for (int g = blockIdx.x * 256 + threadIdx.x; g < NG; g += stride) {
    float4 s = scores4[g];
    float sv[4] = {s.x, s.y, s.z, s.w};
#pragma unroll
    for (int k = 0; k < 4; ++k) {
      unsigned bits = __float_as_uint(sv[k]);
      int n = g * 4 + k;
      if (bits > thr) {
        unsigned pos = atomicAdd(&meta[7], 1u);
        if (pos < (unsigned)PREK) { laS[pos] = sv[k]; laI[pos] = (unsigned)n; }
      } else if (bits == thr) {
        unsigned pos = atomicAdd(&meta[8], 1u);
        if (pos < (unsigned)LISTB_CAP) lb[pos] = (unsigned)n;
      }
    }
  }
}

// ---- fused: tie-resolution + bitonic sort + validW emission ----
__global__ __launch_bounds__(1024) void k_select(const unsigned* __restrict__ meta,
                                                 const float* __restrict__ laS,
                                                 const unsigned* __restrict__ laI,
                                                 const unsigned* __restrict__ lb,
                                                 float* __restrict__ topS,
                                                 unsigned* __restrict__ topI,
                                                 unsigned long long* __restrict__ validW) {
  __shared__ unsigned arrB[LISTB_CAP];            // 32 KB
  __shared__ unsigned long long arr[PREK];        // 32 KB
  int t = threadIdx.x;
  unsigned E = meta[6];
  unsigned G = meta[7];
  unsigned cntB = meta[8];
  if (cntB > (unsigned)LISTB_CAP) cntB = LISTB_CAP;
  unsigned thr = (meta[0] << 20) | (meta[2] << 10) | meta[12];

  if (E != 0) {                                   // uniform branch
    int n2 = 2;
    while ((unsigned)n2 < cntB) n2 <<= 1;
    for (int i = t; i < n2; i += 1024) arrB[i] = (i < (int)cntB) ? lb[i] : 0xFFFFFFFFu;
    __syncthreads();
    if (cntB != E) {
      for (int k = 2; k <= n2; k <<= 1) {
        for (int j = k >> 1; j > 0; j >>= 1) {
          for (int p = t; p < n2 / 2; p += 1024) {
            int i = ((p / j) * (2 * j)) + (p % j);
            int l = i + j;
            bool up = ((i & k) == 0);
            unsigned a = arrB[i], b = arrB[l];
            if ((a > b) == up) { arrB[i] = b; arrB[l] = a; }
          }
          __syncthreads();
        }
      }
    }
    for (int i = t; i < (int)E; i += 1024)
      arr[G + i] = ((unsigned long long)thr << 32) | (unsigned long long)(~arrB[i]);
  }
  __syncthreads();
  for (int i = t; i < PREK; i += 1024)
    if (i < (int)G)
      arr[i] = ((unsigned long long)__float_as_uint(laS[i]) << 32) |
               (unsigned long long)(~laI[i]);
  __syncthreads();
  for (int k = 2; k <= PREK; k <<= 1) {
    for (int j = k >> 1; j > 0; j >>= 1) {
      for (int p = t; p < PREK / 2; p += 1024) {
        int i = ((p / j) * (2 * j)) + (p % j);
        int l = i + j;
        bool up = ((i & k) == 0); // descending
        unsigned long long a = arr[i], b = arr[l];
        if ((a < b) == up) { arr[i] = b; arr[l] = a; }
      }
      __syncthreads();
    }
  }
  for (int i = t; i < PREK; i += 1024) {
    unsigned long long key = arr[i];
    unsigned sb = (unsigned)(key >> 32);
    topS[i] = __uint_as_float(sb);
    topI[i] = ~((unsigned)key);
    unsigned long long bal = __ballot(sb != 0);
    if ((t & 63) == 0) validW[i >> 6] = bal;
  }
}

// ---- decode selected boxes ----
__global__ void k_decode(const float* __restrict__ cls, const float* __restrict__ box,
                         const float* __restrict__ dir, const float* __restrict__ anc,
                         const unsigned* __restrict__ topI,
                         float* __restrict__ tb, float4* __restrict__ b4,
                         unsigned* __restrict__ label) {
  int i = blockIdx.x * blockDim.x + threadIdx.x;
  if (i >= PREK) return;
  size_t idx = (size_t)topI[i];
  const float* a = anc + idx * 7;
  const float* b = box + idx * 7;
  float xa = a[0], ya = a[1], za = a[2], dxa = a[3], dya = a[4], dza = a[5], ra = a[6];
  float xt = b[0], yt = b[1], zt = b[2], dxt = b[3], dyt = b[4], dzt = b[5], rt = b[6];
  za = za + dza * 0.5f;
  float diagl = sqrtf(dxa * dxa + dya * dya);
  float xg = xt * diagl + xa;
  float yg = yt * diagl + ya;
  float zg = zt * dza + za;
  float dxg = (float)exp((double)dxt) * dxa;
  float dyg = (float)exp((double)dyt) * dya;
  float dzg = (float)exp((double)dzt) * dza;
  float rg = rt + ra;
  zg = zg - dzg * 0.5f;
  float d0 = dir[idx * 2], d1 = dir[idx * 2 + 1];
  float dl = (d1 > d0) ? 1.0f : 0.0f;
  float val = rg - DIR_OFFSET;
  val = val - floorf(val / PERIOD) * PERIOD;
  float rot = val + DIR_OFFSET + PERIOD * dl;
  float l0 = cls[idx * 3 + 0];
  float l1 = cls[idx * 3 + 1];
  float l2 = cls[idx * 3 + 2];
  unsigned lab = 1;
  float bestl = l0;
  if (l1 > bestl) { bestl = l1; lab = 2; }
  if (l2 > bestl) { bestl = l2; lab = 3; }
  tb[i * 7 + 0] = xg; tb[i * 7 + 1] = yg; tb[i * 7 + 2] = zg;
  tb[i * 7 + 3] = dxg; tb[i * 7 + 4] = dyg; tb[i * 7 + 5] = dzg;
  tb[i * 7 + 6] = rot;
  float X1 = xg - dxg * 0.5f, X2 = xg + dxg * 0.5f;
  float Y1 = yg - dyg * 0.5f, Y2 = yg + dyg * 0.5f;
  b4[i] = make_float4(X1, Y1, X2, Y2);
  label[i] = lab;
}

// ---- pairwise IoU bitmask (row-major) + 128-chunk diag blocks ----
// diag2 layout (u64): [chunk 0..31][rowHalf 0..1][lane 0..63][word 0..1]
// row r: chunk C=r>>7, half=(r>>6)&1, l=r&63; words = mask[r][2C], mask[r][2C+1]
__global__ __launch_bounds__(256) void k_maskgen(const float4* __restrict__ b4,
                                                 unsigned long long* __restrict__ mask,
                                                 unsigned long long* __restrict__ diag2) {
  __shared__ float4 sb[PREK];   // 64 KB
  int t = threadIdx.x;
  for (int i = t; i < PREK; i += 256) sb[i] = b4[i];
  __syncthreads();
  int lane = t & 63, wv = t >> 6;
  for (int k = wv; k < 16; k += 4) {
    int r = blockIdx.x + (k << 8);
    float4 bi = sb[r];
    float A = (bi.z - bi.x) * (bi.w - bi.y);
    unsigned long long myword = 0;
    unsigned long long d0 = 0, d1 = 0;
    int w0 = r >> 6;
    int b2 = (r >> 7) << 1;
    for (int w = w0; w < 64; ++w) {
      int j = (w << 6) + lane;
      float4 bj = sb[j];
      float ix = fminf(bi.z, bj.z) - fmaxf(bi.x, bj.x); ix = fmaxf(ix, 0.0f);
      float iy = fminf(bi.w, bj.w) - fmaxf(bi.y, bj.y); iy = fmaxf(iy, 0.0f);
      float inter = ix * iy;
      float Aj = (bj.z - bj.x) * (bj.w - bj.y);
      float iou = inter / (A + Aj - inter + 1e-6f);
      unsigned long long word = __ballot(j > r && iou > IOU_THRESH);
      if (lane == w) myword = word;
      if (w == b2) d0 = word;          // uniform compares; ballot is uniform
      if (w == b2 + 1) d1 = word;
    }
    mask[((size_t)r << 6) + lane] = myword;
    if (lane == 0) {
      unsigned long long* dp = diag2 +
          ((size_t)(r >> 7) * 256 + (size_t)((r >> 6) & 1) * 128 + (size_t)(r & 63) * 2);
      dp[0] = d0; dp[1] = d1;
    }
  }
}

// ---- fused greedy NMS (wave 0, 128-box chunks, early-exit) + output build ----
__global__ __launch_bounds__(512) void k_tail(const float* __restrict__ topS,
                                              const float* __restrict__ tb,
                                              const unsigned* __restrict__ label,
                                              const unsigned long long* __restrict__ validW,
                                              const unsigned long long* __restrict__ mask,
                                              const unsigned long long* __restrict__ diag2,
                                              float* __restrict__ out) {
  __shared__ unsigned long long kwS[64];
  __shared__ int part[512];
  __shared__ short keptList[PREK];
  __shared__ short nonKept[PREK];
  int t = threadIdx.x;
  if (t < 64) {
    int lane = t;
    unsigned long long valid_l = validW[lane];
    unsigned long long removed = 0, keep_l = 0;
    const uint4* d4 = (const uint4*)diag2;   // 128 uint4 per chunk
    uint4 dA = d4[lane];                      // chunk 0, row lane
    uint4 dB = d4[64 + lane];                 // chunk 0, row 64+lane
    int keptTotal = 0;
    for (int c = 0; c < 32; ++c) {
      uint4 dA1 = dA, dB1 = dB;
      if (c + 1 < 32) {
        dA1 = d4[(c + 1) * 128 + lane];
        dB1 = d4[(c + 1) * 128 + 64 + lane];
      }
      unsigned long long rem0 = rdl64(removed, 2 * c);
      unsigned long long rem1 = rdl64(removed, 2 * c + 1);
      unsigned long long val0 = rdl64(valid_l, 2 * c);
      unsigned long long val1 = rdl64(valid_l, 2 * c + 1);
      unsigned long long p0 = val0 & ~rem0;
      unsigned long long p1 = val1 & ~rem1;
      unsigned long long k0 = 0, k1 = 0;
      // greedy within chunk: word0 fully first (upper-tri), then word1
      while (p0) {
        int b = __ffsll((long long)p0) - 1;
        b = __builtin_amdgcn_readfirstlane(b);
        k0 |= (1ull << b);
        unsigned long long r0 = rl2(dA.x, dA.y, b);   // row b word 2c
        unsigned long long r1 = rl2(dA.z, dA.w, b);   // row b word 2c+1
        p0 &= (p0 - 1);
        p0 &= ~r0;
        p1 &= ~r1;
      }
      while (p1) {
        int b = __ffsll((long long)p1) - 1;
        b = __builtin_amdgcn_readfirstlane(b);
        k1 |= (1ull << b);
        unsigned long long r1 = rl2(dB.z, dB.w, b);   // row 64+b word 2c+1
        p1 &= (p1 - 1);
        p1 &= ~r1;
      }
      if (lane == 2 * c) keep_l = k0;
      if (lane == 2 * c + 1) keep_l = k1;
      keptTotal += (int)__popcll(k0) + (int)__popcll(k1);
      if (keptTotal >= POSTK) break;   // exact: later keep flags can't reach output
      // batched row-OR: lane l ORs word l of every kept row in this chunk
      unsigned long long kw0 = k0, kw1 = k1;
      size_t rowbase = ((size_t)c << 7);
      while (kw0 | kw1) {
        unsigned long long vv[16];
        unsigned long long mk[16];
#pragma unroll
        for (int u = 0; u < 16; ++u) {
          bool en = ((kw0 | kw1) != 0);
          int b = 0;
          if (kw0) { b = __ffsll((long long)kw0) - 1; kw0 &= kw0 - 1; }
          else if (kw1) { b = 64 + __ffsll((long long)kw1) - 1; kw1 &= kw1 - 1; }
          mk[u] = en ? ~0ull : 0ull;
          vv[u] = mask[((rowbase + (size_t)b) << 6) + lane];
        }
        unsigned long long o = 0;
#pragma unroll
        for (int u = 0; u < 16; ++u) o |= (vv[u] & mk[u]);
        removed |= o;
      }
      dA = dA1;
      dB = dB1;
    }
    kwS[lane] = keep_l;
  }
  __syncthreads();
  // ---- output phase ----
  int base = t * 8;
  int cnt = 0;
  for (int e = 0; e < 8; ++e) {
    int i = base + e;
    cnt += (int)((kwS[i >> 6] >> (i & 63)) & 1ull);
  }
  part[t] = cnt;
  __syncthreads();
  for (int off = 1; off < 512; off <<= 1) {
    int v = part[t];
    int add = (t >= off) ? part[t - off] : 0;
    __syncthreads();
    part[t] = v + add;
    __syncthreads();
  }
  int kbase = part[t] - cnt;
  int nbase = base - kbase;
  for (int e = 0; e < 8; ++e) {
    int i = base + e;
    bool kp = ((kwS[i >> 6] >> (i & 63)) & 1ull) != 0;
    if (kp) keptList[kbase++] = (short)i;
    else nonKept[nbase++] = (short)i;
  }
  __syncthreads();
  int keptCount = part[511];
  for (int k = t; k < POSTK; k += 512) {
    int i;
    float s;
    if (k < keptCount) { i = keptList[k]; s = topS[i]; }
    else { i = nonKept[k - keptCount]; s = 0.0f; }
    for (int c = 0; c < 7; ++c) out[k * 8 + c] = tb[i * 7 + c];
    out[k * 8 + 7] = s;
    out[POSTK * 8 + k] = (float)label[i];
  }
}

extern "C" void kernel_launch(void* const* d_in, const int* in_sizes, int n_in,
                              void* d_out, int out_size, void* d_ws, size_t ws_size,
                              hipStream_t stream) {
  const float* cls = (const float*)d_in[0];
  const float* box = (const float*)d_in[1];
  const float* dir = (const float*)d_in[2];
  const float* anc = (const float*)d_in[3];
  float* out = (float*)d_out;
  char* ws = (char*)d_ws;
  if (ws_size < WS_NEED) return;

  float* scores = (float*)(ws + oScores);
  unsigned* hist12 = (unsigned*)(ws + oHist12);
  unsigned* histA = (unsigned*)(ws + oHistA);
  unsigned* histB = (unsigned*)(ws + oHistB);
  unsigned* meta = (unsigned*)(ws + oMeta);
  float* laS = (float*)(ws + oListAS);
  unsigned* laI = (unsigned*)(ws + oListAI);
  unsigned* lb = (unsigned*)(ws + oListB);
  float* topS = (float*)(ws + oTopS);
  unsigned* topI = (unsigned*)(ws + oTopI);
  float* tb = (float*)(ws + oTB);
  float4* b4 = (float4*)(ws + oB4);
  unsigned* label = (unsigned*)(ws + oLabel);
  unsigned long long* validW = (unsigned long long*)(ws + oValidW);
  unsigned long long* mask = (unsigned long long*)(ws + oMask);
  unsigned long long* diag2 = (unsigned long long*)(ws + oDiag2);

  hipMemsetAsync(ws + oHist12, 0, (oListAS - oHist12), stream);

  k_scores<<<256, 256, 0, stream>>>((const float4*)cls, (float4*)scores, hist12);
  k_refineA<<<256, 256, 0, stream>>>((const float4*)scores, hist12, histA, meta);
  k_refineB<<<256, 256, 0, stream>>>((const float4*)scores, histA, histB, meta);
  k_compactS<<<256, 256, 0, stream>>>((const float4*)scores, histB, meta, laS, laI, lb);
  k_select<<<1, 1024, 0, stream>>>(meta, laS, laI, lb, topS, topI, validW);
  k_decode<<<PREK / 256, 256, 0, stream>>>(cls, box, dir, anc, topI, tb, b4, label);
  k_maskgen<<<256, 256, 0, stream>>>(b4, mask, diag2);
  k_tail<<<1, 512, 0, stream>>>(topS, tb, label, validW, mask, diag2, out);
}